// Round 13
// baseline (150.513 us; speedup 1.0000x reference)
//
#include <hip/hip_runtime.h>
#include <hip/hip_bf16.h>

// SO3TensorProductLayer: out = relu(128*(x (x) x) @ W1 + b1) @ W2 + b2
// v13 (restored — best proven state, 150.4us, absmax 1.0).
// v14 post-mortem: phase-switch removal was semantically identical to
// v13 (audited 3x) yet failed absmax 10.0 on HW — second instance of a
// register-array restructure near the 2-wave cap miscompiling (v4 was
// the first). Gain was <=4us; abandoned per one-strike discipline.
// Session ledger: gemm at 7-variant-confirmed ~30% MfmaUtil structural
// plateau; non-gemm pinned at ~90us across 3 rewrites (fixed overhead);
// symmetry fold (-27us) + direct-read prep (-6us) + Pb coalescing
// banked here. This is the practical floor of this decomposition.

typedef __attribute__((ext_vector_type(8))) short short8;   // 8 bf16
typedef __attribute__((ext_vector_type(4))) float floatx4;  // 4 fp32

__device__ __forceinline__ unsigned short f2bf(float f) {
    union { float f; unsigned int u; } v; v.f = f;
    unsigned int r = v.u + 0x7fffu + ((v.u >> 16) & 1u);   // RNE
    return (unsigned short)(r >> 16);
}
__device__ __forceinline__ float bf2f(unsigned short b) {
    union { unsigned int u; float f; } v; v.u = ((unsigned int)b) << 16;
    return v.f;
}

// ---------------------------------------------------------------------------
// prep: blocks 0..639 pack symmetric-folded W1 -> W1p (direct global
// reads, no LDS); 640..671 transpose W2 -> W2T bf16.
// Task (u, isub, cb): u = (z,kc) unit, isub = 4-i subchunk, cb = 64-c blk.
// Wave w -> c16 = cb*4+w; per iL: chunk(c16, i=z*32+isub*4+iL, kc), lane
// (m=lane&15, quad) elem e = W1s[j=kc*32+quad*8+e][i][c16*16+m], where
// W1s = W1[ij]+W1[ji] (j>i), W1[ii] (j==i), 0 (j<i).
// col = base + il*stride (v11 layout): z=0: (kc>>1)*64+(kc&1),2;
// z=1,kc<3: 128+(kc-1),2; z=1,kc=3: 256,1; z=2: 192+(kc-2),2; z=3: 288,1.
__global__ __launch_bounds__(256) void prep_kernel(
    const float* __restrict__ W1, unsigned short* __restrict__ W1p,
    const float* __restrict__ W2, unsigned short* __restrict__ W2T) {
    __shared__ float tile[64][65];
    const int bx = blockIdx.x;
    const int tid = threadIdx.x;
    if (bx < 640) {
        const int u = bx >> 6;
        const int rem = bx & 63;
        const int isub = rem >> 3, cb = rem & 7;
        const int z  = (u < 4) ? 0 : (u < 7) ? 1 : (u < 9) ? 2 : 3;
        const int kc = (u < 4) ? u : (u < 7) ? (u - 3) : (u < 9) ? (u - 5) : 3;
        int base, stride;
        if (z == 0)                { base = (kc >> 1) * 64 + (kc & 1); stride = 2; }
        else if (z == 1 && kc < 3) { base = 128 + (kc - 1);            stride = 2; }
        else if (z == 1)           { base = 256;                       stride = 1; }
        else if (z == 2)           { base = 192 + (kc - 2);            stride = 2; }
        else                       { base = 288;                       stride = 1; }
        const int j0g = kc * 32;
        const int w = tid >> 6, lane = tid & 63;
        const int m = lane & 15, quad = lane >> 4;
        const int c16 = cb * 4 + w;
        const int c = c16 * 16 + m;                // global c for this lane
#pragma unroll
        for (int iL = 0; iL < 4; ++iL) {
            const int il = isub * 4 + iL;
            const int ig = z * 32 + il;
            union { unsigned short s[8]; uint4 uu; } o;
#pragma unroll
            for (int e = 0; e < 8; ++e) {
                const int jg = j0g + quad * 8 + e;
                float a = 0.f, b = 0.f;
                if (jg >= ig)                       // uniform when z<kc
                    a = W1[((long)ig * 128 + jg) * 512 + c];
                if (jg > ig)
                    b = W1[((long)jg * 128 + ig) * 512 + c];
                o.s[e] = f2bf(a + b);
            }
            const long col = base + (long)il * stride;
            *(uint4*)(W1p + ((long)c16 * 320 + col) * 512 + lane * 8) = o.uu;
        }
    } else {
        const int t = bx - 640;                // 0..31
        const int r0 = (t & 7) * 64, c0 = (t >> 3) * 64;
        const int R = 512, C = 256;
        const int tr = tid >> 4;
        const int tc4 = (tid & 15) * 4;
#pragma unroll
        for (int pp = 0; pp < 4; ++pp) {
            int r = pp * 16 + tr;
            float4 v = *(const float4*)(W2 + (long)(r0 + r) * C + c0 + tc4);
            tile[r][tc4 + 0] = v.x; tile[r][tc4 + 1] = v.y;
            tile[r][tc4 + 2] = v.z; tile[r][tc4 + 3] = v.w;
        }
        __syncthreads();
#pragma unroll
        for (int pp = 0; pp < 4; ++pp) {
            int cc = pp * 16 + tr;
            union { unsigned short s[4]; uint2 u; } pk;
#pragma unroll
            for (int e = 0; e < 4; ++e) pk.s[e] = f2bf(tile[tc4 + e][cc]);
            *(uint2*)(W2T + (long)(c0 + cc) * R + r0 + tc4) = pk.u;
        }
    }
}

// ---------------------------------------------------------------------------
// gemm_sym: 256 thr = 4 waves (2wm c x 2wn b); wave c32 x b128 (tm=2,tn=8);
// block c64 x b256. Grid 512 flat; L=(n&7)*64+(n>>3): bx=L&15, s=L>>4,
// g=s&3 (unit group), cb=s>>2 (== XCD, A-slice 1.31MB L2-resident).
// Pb record (g,ct,bt) = 512B fragment-packed.

// PHASE2 step: CH=2 chained, per-il advance 1024 u16, wrap &31
#define A_STEP2(Ac00, Ac01, Ac10, Ac11, I)                                 \
    {                                                                      \
        float xi[8];                                                       \
        _Pragma("unroll")                                                  \
        for (int tn = 0; tn < 8; ++tn)                                     \
            xi[tn] = xT[bLloc + tn * 16][(I)];                             \
        _Pragma("unroll")                                                  \
        for (int tn = 0; tn < 8; ++tn) {                                   \
            floatx4 t0 = __builtin_amdgcn_mfma_f32_16x16x32_bf16(          \
                Ac00, Xf[0][tn], zero4, 0, 0, 0);                          \
            t0 = __builtin_amdgcn_mfma_f32_16x16x32_bf16(                  \
                Ac01, Xf[1][tn], t0, 0, 0, 0);                             \
            acc[0][tn] += xi[tn] * t0;                                     \
            floatx4 t1 = __builtin_amdgcn_mfma_f32_16x16x32_bf16(          \
                Ac10, Xf[0][tn], zero4, 0, 0, 0);                          \
            t1 = __builtin_amdgcn_mfma_f32_16x16x32_bf16(                  \
                Ac11, Xf[1][tn], t1, 0, 0, 0);                             \
            acc[1][tn] += xi[tn] * t1;                                     \
        }                                                                  \
        const int p_ = ((I) + 4) & 31; /* wrap: tail reload is harmless */ \
        Ac00 = *(const short8*)(aB00 + (long)p_ * 1024);                   \
        Ac01 = *(const short8*)(aB01 + (long)p_ * 1024);                   \
        Ac10 = *(const short8*)(aB10 + (long)p_ * 1024);                   \
        Ac11 = *(const short8*)(aB11 + (long)p_ * 1024);                   \
    }

// PHASE1H step: CH=1, per-il advance 512 u16, wrap &15
#define H_STEP(Ac0, Ac1, I)                                                \
    {                                                                      \
        float xi[8];                                                       \
        _Pragma("unroll")                                                  \
        for (int tn = 0; tn < 8; ++tn)                                     \
            xi[tn] = xT[bLloc + tn * 16][(I)];                             \
        _Pragma("unroll")                                                  \
        for (int tn = 0; tn < 8; ++tn) {                                   \
            floatx4 t0 = __builtin_amdgcn_mfma_f32_16x16x32_bf16(          \
                Ac0, Xf[0][tn], zero4, 0, 0, 0);                           \
            acc[0][tn] += xi[tn] * t0;                                     \
            floatx4 t1 = __builtin_amdgcn_mfma_f32_16x16x32_bf16(          \
                Ac1, Xf[0][tn], zero4, 0, 0, 0);                           \
            acc[1][tn] += xi[tn] * t1;                                     \
        }                                                                  \
        const int p_ = ((I) + 4) & 15;                                     \
        Ac0 = *(const short8*)(aC0 + (long)p_ * 512);                      \
        Ac1 = *(const short8*)(aC1 + (long)p_ * 512);                      \
    }

__global__ __launch_bounds__(256, 2) void gemm_sym_kernel(
    const float* __restrict__ x,               // [4096][128]
    const unsigned short* __restrict__ W1p,
    unsigned short* __restrict__ Pb) {         // fragment-packed partials
    __shared__ float xT[256][34];
    const int tid = threadIdx.x;
    const int n = blockIdx.x;
    const int L = (n & 7) * 64 + (n >> 3);     // bijective, 512 blocks
    const int bx = L & 15;
    const int s = L >> 4;                      // 0..31
    const int g = s & 3;
    const int cb = s >> 2;                     // == XCD
    const int b0 = bx * 256;
    const int c0 = cb * 64;
    const int i0_2 = (g < 2) ? 0 : (g - 1) * 32;
    const int i0_1 = 32 + (g & 1) * 16 + (g >> 1) * 64;
    const int col2 = g * 64;
    const int col1 = 256 + g * 16;
    const int jc0 = (g == 0) ? 0 : (g == 2) ? 1 : 2;
    const int jc1 = (g == 0) ? 1 : (g == 2) ? 2 : 3;

    // stage 32-i slice for PHASE2
    for (int idx = tid; idx < 256 * 32; idx += 256) {
        int bL = idx >> 5, iL = idx & 31;
        xT[bL][iL] = x[(long)(b0 + bL) * 128 + i0_2 + iL];
    }
    __syncthreads();

    const int wid = tid >> 6;
    const int wm = wid >> 1, wn = wid & 1;
    const int lane = tid & 63;
    const int n16 = lane & 15, quad = lane >> 4;
    const int bBase = b0 + wn * 128;
    const int c16base = (c0 >> 4) + wm * 2;
    const int bLloc = wn * 128 + n16;

    floatx4 acc[2][8];
#pragma unroll
    for (int tm = 0; tm < 2; ++tm)
#pragma unroll
        for (int tn = 0; tn < 8; ++tn) acc[tm][tn] = (floatx4){0.f, 0.f, 0.f, 0.f};
    const floatx4 zero4 = (floatx4){0.f, 0.f, 0.f, 0.f};

    // x B-fragments for the two PHASE2 j-chunks
    short8 Xf[2][8];
#pragma unroll
    for (int ks = 0; ks < 2; ++ks) {
        const int jc = ks ? jc1 : jc0;
#pragma unroll
        for (int tn = 0; tn < 8; ++tn) {
            const float* xp = x + (long)(bBase + tn * 16 + n16) * 128
                                + jc * 32 + quad * 8;
            float4 v0 = *(const float4*)xp;
            float4 v1 = *(const float4*)(xp + 4);
            short8 f;
            f[0] = (short)f2bf(v0.x); f[1] = (short)f2bf(v0.y);
            f[2] = (short)f2bf(v0.z); f[3] = (short)f2bf(v0.w);
            f[4] = (short)f2bf(v1.x); f[5] = (short)f2bf(v1.y);
            f[6] = (short)f2bf(v1.z); f[7] = (short)f2bf(v1.w);
            Xf[ks][tn] = f;
        }
    }

    // ---- PHASE2: 32 il, CH=2 ----
    {
        const unsigned short* aB00 = W1p
            + ((long)(c16base + 0) * 320 + col2) * 512 + lane * 8;
        const unsigned short* aB01 = aB00 + 512;
        const unsigned short* aB10 = W1p
            + ((long)(c16base + 1) * 320 + col2) * 512 + lane * 8;
        const unsigned short* aB11 = aB10 + 512;

        short8 A0_00 = *(const short8*)(aB00);
        short8 A0_01 = *(const short8*)(aB01);
        short8 A0_10 = *(const short8*)(aB10);
        short8 A0_11 = *(const short8*)(aB11);
        short8 A1_00 = *(const short8*)(aB00 + 1 * 1024);
        short8 A1_01 = *(const short8*)(aB01 + 1 * 1024);
        short8 A1_10 = *(const short8*)(aB10 + 1 * 1024);
        short8 A1_11 = *(const short8*)(aB11 + 1 * 1024);
        short8 A2_00 = *(const short8*)(aB00 + 2 * 1024);
        short8 A2_01 = *(const short8*)(aB01 + 2 * 1024);
        short8 A2_10 = *(const short8*)(aB10 + 2 * 1024);
        short8 A2_11 = *(const short8*)(aB11 + 2 * 1024);
        short8 A3_00 = *(const short8*)(aB00 + 3 * 1024);
        short8 A3_01 = *(const short8*)(aB01 + 3 * 1024);
        short8 A3_10 = *(const short8*)(aB10 + 3 * 1024);
        short8 A3_11 = *(const short8*)(aB11 + 3 * 1024);

#pragma unroll 1
        for (int ib = 0; ib < 8; ++ib) {
            const int i = ib * 4;
            A_STEP2(A0_00, A0_01, A0_10, A0_11, i + 0)
            A_STEP2(A1_00, A1_01, A1_10, A1_11, i + 1)
            A_STEP2(A2_00, A2_01, A2_10, A2_11, i + 2)
            A_STEP2(A3_00, A3_01, A3_10, A3_11, i + 3)
        }
    }

    // restage 16-i slice for PHASE1H
    __syncthreads();
    for (int idx = tid; idx < 256 * 16; idx += 256) {
        int bL = idx >> 4, iL = idx & 15;
        xT[bL][iL] = x[(long)(b0 + bL) * 128 + i0_1 + iL];
    }
    __syncthreads();
    // reload Xf[0] from j-chunk 3 (PHASE1H operand)
#pragma unroll
    for (int tn = 0; tn < 8; ++tn) {
        const float* xp = x + (long)(bBase + tn * 16 + n16) * 128
                            + 3 * 32 + quad * 8;
        float4 v0 = *(const float4*)xp;
        float4 v1 = *(const float4*)(xp + 4);
        short8 f;
        f[0] = (short)f2bf(v0.x); f[1] = (short)f2bf(v0.y);
        f[2] = (short)f2bf(v0.z); f[3] = (short)f2bf(v0.w);
        f[4] = (short)f2bf(v1.x); f[5] = (short)f2bf(v1.y);
        f[6] = (short)f2bf(v1.z); f[7] = (short)f2bf(v1.w);
        Xf[0][tn] = f;
    }

    // ---- PHASE1H: 16 il, CH=1 ----
    {
        const unsigned short* aC0 = W1p
            + ((long)(c16base + 0) * 320 + col1) * 512 + lane * 8;
        const unsigned short* aC1 = W1p
            + ((long)(c16base + 1) * 320 + col1) * 512 + lane * 8;
        short8 C0_0 = *(const short8*)(aC0);
        short8 C0_1 = *(const short8*)(aC1);
        short8 C1_0 = *(const short8*)(aC0 + 1 * 512);
        short8 C1_1 = *(const short8*)(aC1 + 1 * 512);
        short8 C2_0 = *(const short8*)(aC0 + 2 * 512);
        short8 C2_1 = *(const short8*)(aC1 + 2 * 512);
        short8 C3_0 = *(const short8*)(aC0 + 3 * 512);
        short8 C3_1 = *(const short8*)(aC1 + 3 * 512);

#pragma unroll 1
        for (int ib = 0; ib < 4; ++ib) {
            const int i = ib * 4;
            H_STEP(C0_0, C0_1, i + 0)
            H_STEP(C1_0, C1_1, i + 1)
            H_STEP(C2_0, C2_1, i + 2)
            H_STEP(C3_0, C3_1, i + 3)
        }
    }

    // store bf16 partials, fragment-packed: record (g,ct,bt) = 512B
#pragma unroll
    for (int tm = 0; tm < 2; ++tm)
#pragma unroll
        for (int tn = 0; tn < 8; ++tn) {
            int ct = c16base + tm;                 // 0..31
            int bt = (bBase >> 4) + tn;            // 0..255
            union { unsigned short s[4]; uint2 u; } pk;
#pragma unroll
            for (int r = 0; r < 4; ++r) pk.s[r] = f2bf(acc[tm][tn][r]);
            *(uint2*)(Pb + (((long)(g * 32 + ct) * 256 + bt) * 64 + lane) * 4)
                = pk.u;
        }
}

// ---------------------------------------------------------------------------
// tail: z-reduce fragment-packed Pb in-register, h = relu(128*sum + b1)
// -> hL (bf16, LDS), then out = h @ W2T + b2.
__global__ __launch_bounds__(256) void tail_kernel(
    const unsigned short* __restrict__ Pb,     // fragment-packed partials
    const float* __restrict__ b1,              // [512]
    const unsigned short* __restrict__ W2T,    // [256][512] bf16
    const float* __restrict__ b2,              // [256]
    float* __restrict__ out) {                 // [4096][256]
    __shared__ unsigned short hL[16][516];
    __shared__ float b1s[512];
    const int tid = threadIdx.x;
    const int bt = blockIdx.x;                 // b0 = bt*16
    b1s[tid] = b1[tid];
    b1s[tid + 256] = b1[tid + 256];
    __syncthreads();

    const int w = tid >> 6, lane = tid & 63;
    const int n16 = lane & 15, quad = lane >> 4;

#pragma unroll
    for (int cc = 0; cc < 8; ++cc) {
        const int ct = cc * 4 + w;             // 0..31, wave-partitioned
        float s0 = 0.f, s1 = 0.f, s2 = 0.f, s3 = 0.f;
#pragma unroll
        for (int z = 0; z < 4; ++z) {
            uint2 u = *(const uint2*)(Pb
                + (((long)(z * 32 + ct) * 256 + bt) * 64 + lane) * 4);
            s0 += bf2f((unsigned short)(u.x & 0xffff));
            s1 += bf2f((unsigned short)(u.x >> 16));
            s2 += bf2f((unsigned short)(u.y & 0xffff));
            s3 += bf2f((unsigned short)(u.y >> 16));
        }
        const int c = ct * 16 + quad * 4;
        float v0 = fmaxf(fmaf(128.f, s0, b1s[c + 0]), 0.f);
        float v1 = fmaxf(fmaf(128.f, s1, b1s[c + 1]), 0.f);
        float v2 = fmaxf(fmaf(128.f, s2, b1s[c + 2]), 0.f);
        float v3 = fmaxf(fmaf(128.f, s3, b1s[c + 3]), 0.f);
        union { unsigned short s[4]; uint2 u; } pk;
        pk.s[0] = f2bf(v0); pk.s[1] = f2bf(v1);
        pk.s[2] = f2bf(v2); pk.s[3] = f2bf(v3);
        *(uint2*)&hL[n16][c] = pk.u;
    }
    __syncthreads();

    const int o0 = w * 64;
    floatx4 acc[4];
#pragma unroll
    for (int tn = 0; tn < 4; ++tn) acc[tn] = (floatx4){0.f, 0.f, 0.f, 0.f};

#pragma unroll 4
    for (int ks = 0; ks < 16; ++ks) {
        short8 Af, Bf[4];
        {
            const unsigned short* p = &hL[n16][ks * 32 + quad * 8];
            union { uint2 u[2]; short8 s; } cvt;
            cvt.u[0] = *(const uint2*)p;
            cvt.u[1] = *(const uint2*)(p + 4);
            Af = cvt.s;
        }
#pragma unroll
        for (int tn = 0; tn < 4; ++tn)
            Bf[tn] = *(const short8*)(W2T + (long)(o0 + tn * 16 + n16) * 512
                                      + ks * 32 + quad * 8);
#pragma unroll
        for (int tn = 0; tn < 4; ++tn)
            acc[tn] = __builtin_amdgcn_mfma_f32_16x16x32_bf16(
                Af, Bf[tn], acc[tn], 0, 0, 0);
    }
#pragma unroll
    for (int tn = 0; tn < 4; ++tn) {
        float bias = b2[o0 + tn * 16 + n16];
#pragma unroll
        for (int r = 0; r < 4; ++r)
            out[(long)(bt * 16 + quad * 4 + r) * 256
                + o0 + tn * 16 + n16] = acc[tn][r] + bias;
    }
}

extern "C" void kernel_launch(void* const* d_in, const int* in_sizes, int n_in,
                              void* d_out, int out_size, void* d_ws, size_t ws_size,
                              hipStream_t stream) {
    const float* x  = (const float*)d_in[0];   // [4096,128]
    const float* W1 = (const float*)d_in[1];   // [16384,512]
    const float* b1 = (const float*)d_in[2];   // [512]
    const float* W2 = (const float*)d_in[3];   // [512,256]
    const float* b2 = (const float*)d_in[4];   // [256]
    float* out = (float*)d_out;                // [4096,256]

    char* ws = (char*)d_ws;
    unsigned short* W1p = (unsigned short*)(ws);                  // 10.49 MB
    unsigned short* W2T = (unsigned short*)(ws + 10485760);       // 0.26 MB
    unsigned short* Pb  = (unsigned short*)(ws + 10485760 + 262144); // 16.78 MB

    prep_kernel<<<dim3(672), 256, 0, stream>>>(W1, W1p, W2, W2T);
    gemm_sym_kernel<<<dim3(512), 256, 0, stream>>>(x, W1p, Pb);
    tail_kernel<<<dim3(256), 256, 0, stream>>>(Pb, b1, W2T, b2, out);
}